// Round 14
// baseline (277.322 us; speedup 1.0000x reference)
//
#include <hip/hip_runtime.h>

#define N_NODES 50000

typedef __attribute__((ext_vector_type(8))) short bf16x8;
typedef __attribute__((ext_vector_type(4))) float f32x4;

__device__ __forceinline__ ushort f2bf(float f) {
    union { float f; unsigned u; } v; v.f = f;
    unsigned r = v.u + 0x7fff + ((v.u >> 16) & 1);   // round-to-nearest-even
    return (ushort)(r >> 16);
}
__device__ __forceinline__ float bf2f(ushort u) {
    union { unsigned u; float f; } v; v.u = ((unsigned)u) << 16;
    return v.f;
}
__device__ __forceinline__ float bf2f_lo(unsigned u) {
    union { unsigned u; float f; } v; v.u = u << 16;
    return v.f;
}
__device__ __forceinline__ float bf2f_hi(unsigned u) {
    union { unsigned u; float f; } v; v.u = u & 0xffff0000u;
    return v.f;
}

__device__ __forceinline__ int eload(const void* ei, int idx, int is64) {
    return is64 ? (int)((const long long*)ei)[idx] : ((const int*)ei)[idx];
}

// ---------------- init: detect index width (block 0) + zero deg ----------
__global__ void k_init(const void* ei, int* flag, int* deg, int n) {
    if (blockIdx.x == 0) {
        __shared__ int bad;
        if (threadIdx.x == 0) bad = 0;
        __syncthreads();
        long long v = ((const long long*)ei)[threadIdx.x];
        if (v < 0 || v >= N_NODES) atomicOr(&bad, 1);
        __syncthreads();
        if (threadIdx.x == 0) *flag = bad ? 0 : 1;
    }
    int i = blockIdx.x * 256 + threadIdx.x;
    if (i < n) deg[i] = 0;
}

// ---------------- CSR build ----------------
__global__ void k_hist(const void* ei, const int* flag, int* deg, int e) {
    int base = (blockIdx.x * blockDim.x + threadIdx.x) * 4;
    if (base >= e) return;
    int is64 = *flag;
    if (base + 4 <= e) {
        int d0 = eload(ei, e + base,     is64);
        int d1 = eload(ei, e + base + 1, is64);
        int d2 = eload(ei, e + base + 2, is64);
        int d3 = eload(ei, e + base + 3, is64);
        atomicAdd(&deg[d0], 1);
        atomicAdd(&deg[d1], 1);
        atomicAdd(&deg[d2], 1);
        atomicAdd(&deg[d3], 1);
    } else {
        for (int i = base; i < e; ++i)
            atomicAdd(&deg[eload(ei, e + i, is64)], 1);
    }
}

// per-block (512) inclusive scan of deg -> rowptr+1 (local); raw block totals
__global__ __launch_bounds__(512)
void k_scanA(const int* __restrict__ deg, int* __restrict__ rp1,
             int* __restrict__ bsum, int n) {
    __shared__ int wsum[8];
    const int i = blockIdx.x * 512 + threadIdx.x;
    const int lane = threadIdx.x & 63, wid = threadIdx.x >> 6;
    int x = (i < n) ? deg[i] : 0;
    #pragma unroll
    for (int off = 1; off < 64; off <<= 1) {
        int y = __shfl_up(x, off, 64);
        if (lane >= off) x += y;
    }
    if (lane == 63) wsum[wid] = x;
    __syncthreads();
    if (wid == 0 && lane < 8) {
        int s = wsum[lane];
        #pragma unroll
        for (int off = 1; off < 8; off <<= 1) {
            int y = __shfl_up(s, off, 64);
            if (lane >= off) s += y;
        }
        wsum[lane] = s;
    }
    __syncthreads();
    int incl = x + (wid > 0 ? wsum[wid - 1] : 0);
    if (i < n) rp1[i] = incl;
    if (threadIdx.x == 0) bsum[blockIdx.x] = wsum[7];
}

// add block offsets (reduces bsum[<bx] in-block); emit rowptr, cur, dinv
__global__ __launch_bounds__(512)
void k_scanC(const int* __restrict__ deg, int* __restrict__ rowptr,
             const int* __restrict__ bsum, int* __restrict__ cur,
             float* __restrict__ dinv, int n, int nb) {
    __shared__ int spart[2];
    if (threadIdx.x < 128) {
        int v = (threadIdx.x < nb && (int)threadIdx.x < (int)blockIdx.x)
                ? bsum[threadIdx.x] : 0;
        #pragma unroll
        for (int o = 32; o; o >>= 1) v += __shfl_down(v, o, 64);
        if ((threadIdx.x & 63) == 0) spart[threadIdx.x >> 6] = v;
    }
    __syncthreads();
    const int off = spart[0] + spart[1];
    const int i = blockIdx.x * 512 + threadIdx.x;
    if (i >= n) return;
    const int d = deg[i];
    const int incl = rowptr[i + 1] + off;
    rowptr[i + 1] = incl;
    cur[i] = incl - d;
    dinv[i] = rsqrtf((float)(d + 1));   // +1 self-loop
    if (i == 0) rowptr[0] = 0;
}

// counting-sort scatter, XCD-phase partitioned by dst range
__global__ void k_fill(const void* ei, const int* flag, int* cur, int* adj, int e) {
    const int phase = blockIdx.x & 7;
    const int lo = phase * (N_NODES / 8);
    const int hi = lo + (N_NODES / 8);
    const int i = (blockIdx.x >> 3) * 256 + threadIdx.x;
    if (i >= e) return;
    const int is64 = *flag;
    const int d = eload(ei, e + i, is64);
    if (d >= lo && d < hi) {
        const int s = eload(ei, i, is64);
        adj[atomicAdd(&cur[d], 1)] = s;
    }
}

// ---------------- weight transpose to bf16: Bt[n][k] = bf16(W[k][n]) -----
__global__ void k_splitW(const float* __restrict__ W1, const float* __restrict__ W2,
                         ushort* __restrict__ o1, ushort* __restrict__ o2) {
    int idx = blockIdx.x * 256 + threadIdx.x;
    if (idx < 512 * 128) {                 // W1: K=128, N=512 (Bt1[n][k])
        int nn = idx >> 7, k = idx & 127;
        o1[idx] = f2bf(W1[(size_t)k * 512 + nn]);
    } else {                               // W2: K=512, N=250->256 (Bt2[n][k])
        idx -= 512 * 128;
        int nn = idx >> 9, k = idx & 511;
        o2[idx] = (nn < 250) ? f2bf(W2[(size_t)k * 250 + nn]) : (ushort)0;
    }
}

// ---------------- pre-scale: xs[i][f] = bf16(dinv[i] * x[i][f]) ----------
__global__ __launch_bounds__(256)
void k_scale(const float* __restrict__ x, const float* __restrict__ dinv,
             ushort* __restrict__ xs, int n) {
    int idx = blockIdx.x * 256 + threadIdx.x;      // over n*64 u32 slots
    if (idx >= n * 64) return;
    int i = idx >> 6;
    float2 v = ((const float2*)x)[idx];
    float d = dinv[i];
    ((unsigned*)xs)[idx] = (unsigned)f2bf(d * v.x) | ((unsigned)f2bf(d * v.y) << 16);
}

// ---------------- pull layer 1 (F=128, xs bf16) -> bf16, 1 row/wave ------
__global__ __launch_bounds__(256)
void k_pull128b(const int* __restrict__ rowptr, const int* __restrict__ adj,
                const float* __restrict__ dinv, const ushort* __restrict__ xs,
                ushort* __restrict__ ohi, int n) {
    const int i = blockIdx.x * 4 + (threadIdx.x >> 6);
    if (i >= n) return;
    const int lane = threadIdx.x & 63;
    const unsigned* xs32 = (const unsigned*)xs;
    unsigned u = xs32[(size_t)i * 64 + lane];
    float a0 = bf2f_lo(u), a1 = bf2f_hi(u);
    int j = rowptr[i];
    const int end = rowptr[i + 1];
    for (; j + 8 <= end; j += 8) {
        int s0 = adj[j],     s1 = adj[j + 1], s2 = adj[j + 2], s3 = adj[j + 3];
        int s4 = adj[j + 4], s5 = adj[j + 5], s6 = adj[j + 6], s7 = adj[j + 7];
        unsigned u0 = xs32[(size_t)s0 * 64 + lane];
        unsigned u1 = xs32[(size_t)s1 * 64 + lane];
        unsigned u2 = xs32[(size_t)s2 * 64 + lane];
        unsigned u3 = xs32[(size_t)s3 * 64 + lane];
        unsigned u4 = xs32[(size_t)s4 * 64 + lane];
        unsigned u5 = xs32[(size_t)s5 * 64 + lane];
        unsigned u6 = xs32[(size_t)s6 * 64 + lane];
        unsigned u7 = xs32[(size_t)s7 * 64 + lane];
        a0 += bf2f_lo(u0) + bf2f_lo(u1) + bf2f_lo(u2) + bf2f_lo(u3);
        a1 += bf2f_hi(u0) + bf2f_hi(u1) + bf2f_hi(u2) + bf2f_hi(u3);
        a0 += bf2f_lo(u4) + bf2f_lo(u5) + bf2f_lo(u6) + bf2f_lo(u7);
        a1 += bf2f_hi(u4) + bf2f_hi(u5) + bf2f_hi(u6) + bf2f_hi(u7);
    }
    for (; j + 4 <= end; j += 4) {
        int s0 = adj[j], s1 = adj[j + 1], s2 = adj[j + 2], s3 = adj[j + 3];
        unsigned u0 = xs32[(size_t)s0 * 64 + lane];
        unsigned u1 = xs32[(size_t)s1 * 64 + lane];
        unsigned u2 = xs32[(size_t)s2 * 64 + lane];
        unsigned u3 = xs32[(size_t)s3 * 64 + lane];
        a0 += bf2f_lo(u0) + bf2f_lo(u1) + bf2f_lo(u2) + bf2f_lo(u3);
        a1 += bf2f_hi(u0) + bf2f_hi(u1) + bf2f_hi(u2) + bf2f_hi(u3);
    }
    for (; j < end; ++j) {
        unsigned us = xs32[(size_t)adj[j] * 64 + lane];
        a0 += bf2f_lo(us);
        a1 += bf2f_hi(us);
    }
    const float di = dinv[i];
    a0 *= di; a1 *= di;
    ((unsigned*)ohi)[(size_t)i * 64 + lane] =
        (unsigned)f2bf(a0) | ((unsigned)f2bf(a1) << 16);
}

// ---------------- pull layer 2 (F=250, t bf16 ld=256), 1 row/wave --------
__global__ __launch_bounds__(256)
void k_pull250v(const int* __restrict__ rowptr, const int* __restrict__ adj,
                const float* __restrict__ dinv, const ushort* __restrict__ t,
                const float* __restrict__ bias, float* __restrict__ out, int n) {
    const int i = blockIdx.x * 4 + (threadIdx.x >> 6);
    if (i >= n) return;
    const int lane = threadIdx.x & 63;
    const uint2* t2 = (const uint2*)t;   // [row][64] x uint2 (256 bf16)
    uint2 u = t2[(size_t)i * 64 + lane];
    float a0 = bf2f_lo(u.x), a1 = bf2f_hi(u.x);
    float a2 = bf2f_lo(u.y), a3 = bf2f_hi(u.y);
    int j = rowptr[i];
    const int end = rowptr[i + 1];
    for (; j + 8 <= end; j += 8) {
        int s0 = adj[j],     s1 = adj[j + 1], s2 = adj[j + 2], s3 = adj[j + 3];
        int s4 = adj[j + 4], s5 = adj[j + 5], s6 = adj[j + 6], s7 = adj[j + 7];
        uint2 u0 = t2[(size_t)s0 * 64 + lane];
        uint2 u1 = t2[(size_t)s1 * 64 + lane];
        uint2 u2 = t2[(size_t)s2 * 64 + lane];
        uint2 u3 = t2[(size_t)s3 * 64 + lane];
        uint2 u4 = t2[(size_t)s4 * 64 + lane];
        uint2 u5 = t2[(size_t)s5 * 64 + lane];
        uint2 u6 = t2[(size_t)s6 * 64 + lane];
        uint2 u7 = t2[(size_t)s7 * 64 + lane];
        a0 += bf2f_lo(u0.x) + bf2f_lo(u1.x) + bf2f_lo(u2.x) + bf2f_lo(u3.x);
        a1 += bf2f_hi(u0.x) + bf2f_hi(u1.x) + bf2f_hi(u2.x) + bf2f_hi(u3.x);
        a2 += bf2f_lo(u0.y) + bf2f_lo(u1.y) + bf2f_lo(u2.y) + bf2f_lo(u3.y);
        a3 += bf2f_hi(u0.y) + bf2f_hi(u1.y) + bf2f_hi(u2.y) + bf2f_hi(u3.y);
        a0 += bf2f_lo(u4.x) + bf2f_lo(u5.x) + bf2f_lo(u6.x) + bf2f_lo(u7.x);
        a1 += bf2f_hi(u4.x) + bf2f_hi(u5.x) + bf2f_hi(u6.x) + bf2f_hi(u7.x);
        a2 += bf2f_lo(u4.y) + bf2f_lo(u5.y) + bf2f_lo(u6.y) + bf2f_lo(u7.y);
        a3 += bf2f_hi(u4.y) + bf2f_hi(u5.y) + bf2f_hi(u6.y) + bf2f_hi(u7.y);
    }
    for (; j + 4 <= end; j += 4) {
        int s0 = adj[j], s1 = adj[j + 1], s2 = adj[j + 2], s3 = adj[j + 3];
        uint2 u0 = t2[(size_t)s0 * 64 + lane];
        uint2 u1 = t2[(size_t)s1 * 64 + lane];
        uint2 u2 = t2[(size_t)s2 * 64 + lane];
        uint2 u3 = t2[(size_t)s3 * 64 + lane];
        a0 += bf2f_lo(u0.x) + bf2f_lo(u1.x) + bf2f_lo(u2.x) + bf2f_lo(u3.x);
        a1 += bf2f_hi(u0.x) + bf2f_hi(u1.x) + bf2f_hi(u2.x) + bf2f_hi(u3.x);
        a2 += bf2f_lo(u0.y) + bf2f_lo(u1.y) + bf2f_lo(u2.y) + bf2f_lo(u3.y);
        a3 += bf2f_hi(u0.y) + bf2f_hi(u1.y) + bf2f_hi(u2.y) + bf2f_hi(u3.y);
    }
    for (; j < end; ++j) {
        uint2 us = t2[(size_t)adj[j] * 64 + lane];
        a0 += bf2f_lo(us.x); a1 += bf2f_hi(us.x);
        a2 += bf2f_lo(us.y); a3 += bf2f_hi(us.y);
    }
    const float d = dinv[i];
    const int c0 = lane * 4;
    if (lane < 62) {
        float2 b0 = *(const float2*)&bias[c0];
        float2 b1 = *(const float2*)&bias[c0 + 2];
        float2 o0, o1;
        o0.x = fmaxf(d * a0 + b0.x, 0.0f);
        o0.y = fmaxf(d * a1 + b0.y, 0.0f);
        o1.x = fmaxf(d * a2 + b1.x, 0.0f);
        o1.y = fmaxf(d * a3 + b1.y, 0.0f);
        *(float2*)&out[(size_t)i * 250 + c0] = o0;
        *(float2*)&out[(size_t)i * 250 + c0 + 2] = o1;
    } else if (lane == 62) {   // cols 248,249
        float2 b0 = *(const float2*)&bias[248];
        float2 o0;
        o0.x = fmaxf(d * a0 + b0.x, 0.0f);
        o0.y = fmaxf(d * a1 + b0.y, 0.0f);
        *(float2*)&out[(size_t)i * 250 + 248] = o0;
    }
}

// ---------------- fused double-GEMM: per 64-row panel --------------------
// stage1: h1s = relu(A1[brow:+64] @ W1 + b1)  -> LDS [64][520] bf16
// stage2: t[brow:+64] = dinv ⊙ (h1s @ W2)     -> global [row][256] bf16
// 512 threads = 8 waves. Stage1: wave w owns cols [w*64,+64) in two
// 32-col halves (acc[4][2]). Stage2: wave w owns cols [w*32,+32).
// Fragments loaded directly from global (W1/W2 are L2-resident; A1 rows
// are block-private). Swapped mfma operands as in prior verified kernels.
#define H1PAD 520   // 512 + 8 bf16 -> row stride 1040 B, 2-way-free banks

__global__ __launch_bounds__(512, 4)
void k_fused(const ushort* __restrict__ A1, const ushort* __restrict__ Bt1,
             const ushort* __restrict__ Bt2, const float* __restrict__ b1,
             const float* __restrict__ dinv, ushort* __restrict__ t, int M) {
    __shared__ __align__(16) ushort h1s[64 * H1PAD];   // 66,560 B
    const int tid  = threadIdx.x;
    const int lane = tid & 63;
    const int w    = tid >> 6;    // 0..7
    const int g    = lane >> 4;   // 0..3
    const int lr   = lane & 15;
    const int brow = blockIdx.x * 64;

    // ---- stage 1 ----
    #pragma unroll
    for (int half = 0; half < 2; ++half) {
        f32x4 acc[4][2] = {};
        const ushort* aB[4];
        const ushort* bB[2];
        #pragma unroll
        for (int mt = 0; mt < 4; ++mt)
            aB[mt] = A1 + (size_t)(brow + mt * 16 + lr) * 128 + g * 8;
        #pragma unroll
        for (int nt = 0; nt < 2; ++nt)
            bB[nt] = Bt1 + (size_t)(w * 64 + half * 32 + nt * 16 + lr) * 128 + g * 8;
        #pragma unroll
        for (int kk = 0; kk < 128; kk += 32) {
            bf16x8 af[4], bh[2];
            #pragma unroll
            for (int mt = 0; mt < 4; ++mt) af[mt] = *(const bf16x8*)(aB[mt] + kk);
            #pragma unroll
            for (int nt = 0; nt < 2; ++nt) bh[nt] = *(const bf16x8*)(bB[nt] + kk);
            #pragma unroll
            for (int mt = 0; mt < 4; ++mt)
                #pragma unroll
                for (int nt = 0; nt < 2; ++nt)
                    acc[mt][nt] = __builtin_amdgcn_mfma_f32_16x16x32_bf16(bh[nt], af[mt], acc[mt][nt], 0, 0, 0);
        }
        #pragma unroll
        for (int mt = 0; mt < 4; ++mt) {
            const int r = mt * 16 + lr;
            #pragma unroll
            for (int nt = 0; nt < 2; ++nt) {
                const int c0 = w * 64 + half * 32 + nt * 16 + g * 4;
                const float4 bv = *(const float4*)&b1[c0];
                float v0 = fmaxf(acc[mt][nt][0] + bv.x, 0.0f);
                float v1 = fmaxf(acc[mt][nt][1] + bv.y, 0.0f);
                float v2 = fmaxf(acc[mt][nt][2] + bv.z, 0.0f);
                float v3 = fmaxf(acc[mt][nt][3] + bv.w, 0.0f);
                uint2 pk;
                pk.x = (unsigned)f2bf(v0) | ((unsigned)f2bf(v1) << 16);
                pk.y = (unsigned)f2bf(v2) | ((unsigned)f2bf(v3) << 16);
                *(uint2*)&h1s[r * H1PAD + c0] = pk;
            }
        }
    }
    __syncthreads();

    // ---- stage 2 ----
    {
        f32x4 acc[4][2] = {};
        const ushort* lB[4];
        const ushort* bB[2];
        #pragma unroll
        for (int mt = 0; mt < 4; ++mt)
            lB[mt] = h1s + (mt * 16 + lr) * H1PAD + g * 8;
        #pragma unroll
        for (int nt = 0; nt < 2; ++nt)
            bB[nt] = Bt2 + (size_t)(w * 32 + nt * 16 + lr) * 512 + g * 8;
        #pragma unroll 4
        for (int kk = 0; kk < 512; kk += 32) {
            bf16x8 af[4], bh[2];
            #pragma unroll
            for (int mt = 0; mt < 4; ++mt) af[mt] = *(const bf16x8*)(lB[mt] + kk);
            #pragma unroll
            for (int nt = 0; nt < 2; ++nt) bh[nt] = *(const bf16x8*)(bB[nt] + kk);
            #pragma unroll
            for (int mt = 0; mt < 4; ++mt)
                #pragma unroll
                for (int nt = 0; nt < 2; ++nt)
                    acc[mt][nt] = __builtin_amdgcn_mfma_f32_16x16x32_bf16(bh[nt], af[mt], acc[mt][nt], 0, 0, 0);
        }
        #pragma unroll
        for (int mt = 0; mt < 4; ++mt) {
            const int gr = brow + mt * 16 + lr;
            const float rs = dinv[gr];
            #pragma unroll
            for (int nt = 0; nt < 2; ++nt) {
                const int c0 = w * 32 + nt * 16 + g * 4;
                uint2 pk;
                pk.x = (unsigned)f2bf(acc[mt][nt][0] * rs) |
                       ((unsigned)f2bf(acc[mt][nt][1] * rs) << 16);
                pk.y = (unsigned)f2bf(acc[mt][nt][2] * rs) |
                       ((unsigned)f2bf(acc[mt][nt][3] * rs) << 16);
                *(uint2*)&t[(size_t)gr * 256 + c0] = pk;
            }
        }
    }
}

extern "C" void kernel_launch(void* const* d_in, const int* in_sizes, int n_in,
                              void* d_out, int out_size, void* d_ws, size_t ws_size,
                              hipStream_t stream) {
    const float* x  = (const float*)d_in[0];
    const void*  ei = d_in[1];
    const float* W1 = (const float*)d_in[2];
    const float* b1 = (const float*)d_in[3];
    const float* W2 = (const float*)d_in[4];
    const float* b2 = (const float*)d_in[5];
    float* out = (float*)d_out;

    const int N = N_NODES;
    const int E = in_sizes[1] / 2;
    const int MPAD = 50048;             // 782 * 64
    const int NSCB = (N + 511) / 512;   // 98 scan blocks

    // ---- workspace layout (~55 MB) ----
    char* base = (char*)d_ws;
    int*   flag   = (int*)base;                        // 256 B slot
    int*   deg    = (int*)(base + 256);                // [51200]
    int*   rowptr = deg + 51200;
    int*   cur    = rowptr + 51200;
    float* dinv   = (float*)(cur + 51200);
    int*   bsum   = (int*)(dinv + 51200);              // [128]
    int*   adj    = bsum + 128;                        // [E]
    char*  p      = (char*)(adj + ((E + 63) & ~63));
    ushort* A1hi  = (ushort*)p;  p += (size_t)MPAD * 128 * 2;  // bf16 agg1
    ushort* tbuf  = (ushort*)p;  p += (size_t)MPAD * 256 * 2;  // bf16 t (own buffer!)
    ushort* Bt1   = (ushort*)p;  p += 512 * 128 * 2;
    ushort* Bt2   = (ushort*)p;  p += 256 * 512 * 2;
    ushort* xs    = (ushort*)p;  p += (size_t)MPAD * 128 * 2;  // bf16 dinv*x

    // 1. CSR build + normalization
    k_init<<<(N + 255) / 256, 256, 0, stream>>>(ei, flag, deg, N);
    k_hist<<<(E / 4 + 255) / 256, 256, 0, stream>>>(ei, flag, deg, E);
    k_scanA<<<NSCB, 512, 0, stream>>>(deg, rowptr + 1, bsum, N);
    k_scanC<<<NSCB, 512, 0, stream>>>(deg, rowptr, bsum, cur, dinv, N, NSCB);
    k_fill<<<((E + 255) / 256) * 8, 256, 0, stream>>>(ei, flag, cur, adj, E);

    // 2. weight prep (both) + pre-scaled features
    k_splitW<<<(512 * 128 + 256 * 512) / 256, 256, 0, stream>>>(W1, W2, Bt1, Bt2);
    k_scale<<<(N * 64 + 255) / 256, 256, 0, stream>>>(x, dinv, xs, N);

    // 3. layer-1 aggregation -> A1 (bf16)  [N,128]
    k_pull128b<<<(N + 3) / 4, 256, 0, stream>>>(rowptr, adj, dinv, xs, A1hi, N);

    // 4+5. fused: t = dinv ⊙ (relu(A1@W1+b1) @ W2)   [N,256]
    k_fused<<<MPAD / 64, 512, 0, stream>>>(A1hi, Bt1, Bt2, b1, dinv, tbuf, N);

    // 6. layer-2 aggregation + bias + relu -> out  [N,250]
    k_pull250v<<<(N + 3) / 4, 256, 0, stream>>>(rowptr, adj, dinv, tbuf, b2, out, N);
}

// Round 15
// 264.815 us; speedup vs baseline: 1.0472x; 1.0472x over previous
//
#include <hip/hip_runtime.h>

#define N_NODES 50000

typedef __attribute__((ext_vector_type(8))) short bf16x8;
typedef __attribute__((ext_vector_type(4))) float f32x4;

__device__ __forceinline__ ushort f2bf(float f) {
    union { float f; unsigned u; } v; v.f = f;
    unsigned r = v.u + 0x7fff + ((v.u >> 16) & 1);   // round-to-nearest-even
    return (ushort)(r >> 16);
}
__device__ __forceinline__ float bf2f(ushort u) {
    union { unsigned u; float f; } v; v.u = ((unsigned)u) << 16;
    return v.f;
}
__device__ __forceinline__ float bf2f_lo(unsigned u) {
    union { unsigned u; float f; } v; v.u = u << 16;
    return v.f;
}
__device__ __forceinline__ float bf2f_hi(unsigned u) {
    union { unsigned u; float f; } v; v.u = u & 0xffff0000u;
    return v.f;
}

__device__ __forceinline__ int eload(const void* ei, int idx, int is64) {
    return is64 ? (int)((const long long*)ei)[idx] : ((const int*)ei)[idx];
}

// ---------------- init: detect width (blk 0) + zero deg + weight prep ----
__global__ void k_init(const void* ei, int* flag, int* deg, int n,
                       const float* __restrict__ W1, const float* __restrict__ W2,
                       ushort* __restrict__ o1, ushort* __restrict__ o2) {
    if (blockIdx.x == 0) {
        __shared__ int bad;
        if (threadIdx.x == 0) bad = 0;
        __syncthreads();
        long long v = ((const long long*)ei)[threadIdx.x];
        if (v < 0 || v >= N_NODES) atomicOr(&bad, 1);
        __syncthreads();
        if (threadIdx.x == 0) *flag = bad ? 0 : 1;
    }
    int i = blockIdx.x * 256 + threadIdx.x;
    if (i < n) deg[i] = 0;
    // weight transpose to bf16 (same linear index space)
    if (i < 512 * 128) {                    // W1: Bt1[n][k], K=128, N=512
        int nn = i >> 7, k = i & 127;
        o1[i] = f2bf(W1[(size_t)k * 512 + nn]);
    } else if (i < 512 * 128 + 256 * 512) { // W2: Bt2[n][k], K=512, N=250->256
        int idx = i - 512 * 128;
        int nn = idx >> 9, k = idx & 511;
        o2[idx] = (nn < 250) ? f2bf(W2[(size_t)k * 250 + nn]) : (ushort)0;
    }
}

// ---------------- CSR build ----------------
__global__ void k_hist(const void* ei, const int* flag, int* deg, int e) {
    int base = (blockIdx.x * blockDim.x + threadIdx.x) * 4;
    if (base >= e) return;
    int is64 = *flag;
    if (base + 4 <= e) {
        int d0 = eload(ei, e + base,     is64);
        int d1 = eload(ei, e + base + 1, is64);
        int d2 = eload(ei, e + base + 2, is64);
        int d3 = eload(ei, e + base + 3, is64);
        atomicAdd(&deg[d0], 1);
        atomicAdd(&deg[d1], 1);
        atomicAdd(&deg[d2], 1);
        atomicAdd(&deg[d3], 1);
    } else {
        for (int i = base; i < e; ++i)
            atomicAdd(&deg[eload(ei, e + i, is64)], 1);
    }
}

// per-block (512) inclusive scan of deg -> rowptr+1 (local); raw block totals
__global__ __launch_bounds__(512)
void k_scanA(const int* __restrict__ deg, int* __restrict__ rp1,
             int* __restrict__ bsum, int n) {
    __shared__ int wsum[8];
    const int i = blockIdx.x * 512 + threadIdx.x;
    const int lane = threadIdx.x & 63, wid = threadIdx.x >> 6;
    int x = (i < n) ? deg[i] : 0;
    #pragma unroll
    for (int off = 1; off < 64; off <<= 1) {
        int y = __shfl_up(x, off, 64);
        if (lane >= off) x += y;
    }
    if (lane == 63) wsum[wid] = x;
    __syncthreads();
    if (wid == 0 && lane < 8) {
        int s = wsum[lane];
        #pragma unroll
        for (int off = 1; off < 8; off <<= 1) {
            int y = __shfl_up(s, off, 64);
            if (lane >= off) s += y;
        }
        wsum[lane] = s;
    }
    __syncthreads();
    int incl = x + (wid > 0 ? wsum[wid - 1] : 0);
    if (i < n) rp1[i] = incl;
    if (threadIdx.x == 0) bsum[blockIdx.x] = wsum[7];
}

// add block offsets (reduces bsum[<bx] in-block); emit rowptr, cur, dinv
__global__ __launch_bounds__(512)
void k_scanC(const int* __restrict__ deg, int* __restrict__ rowptr,
             const int* __restrict__ bsum, int* __restrict__ cur,
             float* __restrict__ dinv, int n, int nb) {
    __shared__ int spart[2];
    if (threadIdx.x < 128) {
        int v = (threadIdx.x < nb && (int)threadIdx.x < (int)blockIdx.x)
                ? bsum[threadIdx.x] : 0;
        #pragma unroll
        for (int o = 32; o; o >>= 1) v += __shfl_down(v, o, 64);
        if ((threadIdx.x & 63) == 0) spart[threadIdx.x >> 6] = v;
    }
    __syncthreads();
    const int off = spart[0] + spart[1];
    const int i = blockIdx.x * 512 + threadIdx.x;
    if (i >= n) return;
    const int d = deg[i];
    const int incl = rowptr[i + 1] + off;
    rowptr[i + 1] = incl;
    cur[i] = incl - d;
    dinv[i] = rsqrtf((float)(d + 1));   // +1 self-loop
    if (i == 0) rowptr[0] = 0;
}

// counting-sort scatter, XCD-phase partitioned by dst range
__global__ void k_fill(const void* ei, const int* flag, int* cur, int* adj, int e) {
    const int phase = blockIdx.x & 7;
    const int lo = phase * (N_NODES / 8);
    const int hi = lo + (N_NODES / 8);
    const int i = (blockIdx.x >> 3) * 256 + threadIdx.x;
    if (i >= e) return;
    const int is64 = *flag;
    const int d = eload(ei, e + i, is64);
    if (d >= lo && d < hi) {
        const int s = eload(ei, i, is64);
        adj[atomicAdd(&cur[d], 1)] = s;
    }
}

// ---------------- pre-scale: xs[i][f] = bf16(dinv[i] * x[i][f]) ----------
__global__ __launch_bounds__(256)
void k_scale(const float* __restrict__ x, const float* __restrict__ dinv,
             ushort* __restrict__ xs, int n) {
    int idx = blockIdx.x * 256 + threadIdx.x;      // over n*64 u32 slots
    if (idx >= n * 64) return;
    int i = idx >> 6;
    float2 v = ((const float2*)x)[idx];
    float d = dinv[i];
    ((unsigned*)xs)[idx] = (unsigned)f2bf(d * v.x) | ((unsigned)f2bf(d * v.y) << 16);
}

// ---------------- pull layer 1 (F=128, xs bf16) -> bf16, 1 row/wave ------
__global__ __launch_bounds__(256)
void k_pull128b(const int* __restrict__ rowptr, const int* __restrict__ adj,
                const float* __restrict__ dinv, const ushort* __restrict__ xs,
                ushort* __restrict__ ohi, int n) {
    const int i = blockIdx.x * 4 + (threadIdx.x >> 6);
    if (i >= n) return;
    const int lane = threadIdx.x & 63;
    const unsigned* xs32 = (const unsigned*)xs;
    unsigned u = xs32[(size_t)i * 64 + lane];
    float a0 = bf2f_lo(u), a1 = bf2f_hi(u);
    int j = rowptr[i];
    const int end = rowptr[i + 1];
    for (; j + 8 <= end; j += 8) {
        int s0 = adj[j],     s1 = adj[j + 1], s2 = adj[j + 2], s3 = adj[j + 3];
        int s4 = adj[j + 4], s5 = adj[j + 5], s6 = adj[j + 6], s7 = adj[j + 7];
        unsigned u0 = xs32[(size_t)s0 * 64 + lane];
        unsigned u1 = xs32[(size_t)s1 * 64 + lane];
        unsigned u2 = xs32[(size_t)s2 * 64 + lane];
        unsigned u3 = xs32[(size_t)s3 * 64 + lane];
        unsigned u4 = xs32[(size_t)s4 * 64 + lane];
        unsigned u5 = xs32[(size_t)s5 * 64 + lane];
        unsigned u6 = xs32[(size_t)s6 * 64 + lane];
        unsigned u7 = xs32[(size_t)s7 * 64 + lane];
        a0 += bf2f_lo(u0) + bf2f_lo(u1) + bf2f_lo(u2) + bf2f_lo(u3);
        a1 += bf2f_hi(u0) + bf2f_hi(u1) + bf2f_hi(u2) + bf2f_hi(u3);
        a0 += bf2f_lo(u4) + bf2f_lo(u5) + bf2f_lo(u6) + bf2f_lo(u7);
        a1 += bf2f_hi(u4) + bf2f_hi(u5) + bf2f_hi(u6) + bf2f_hi(u7);
    }
    for (; j + 4 <= end; j += 4) {
        int s0 = adj[j], s1 = adj[j + 1], s2 = adj[j + 2], s3 = adj[j + 3];
        unsigned u0 = xs32[(size_t)s0 * 64 + lane];
        unsigned u1 = xs32[(size_t)s1 * 64 + lane];
        unsigned u2 = xs32[(size_t)s2 * 64 + lane];
        unsigned u3 = xs32[(size_t)s3 * 64 + lane];
        a0 += bf2f_lo(u0) + bf2f_lo(u1) + bf2f_lo(u2) + bf2f_lo(u3);
        a1 += bf2f_hi(u0) + bf2f_hi(u1) + bf2f_hi(u2) + bf2f_hi(u3);
    }
    for (; j < end; ++j) {
        unsigned us = xs32[(size_t)adj[j] * 64 + lane];
        a0 += bf2f_lo(us);
        a1 += bf2f_hi(us);
    }
    const float di = dinv[i];
    a0 *= di; a1 *= di;
    ((unsigned*)ohi)[(size_t)i * 64 + lane] =
        (unsigned)f2bf(a0) | ((unsigned)f2bf(a1) << 16);
}

// ---------------- pull layer 2 (F=250, t bf16 ld=256), 1 row/wave --------
__global__ __launch_bounds__(256)
void k_pull250v(const int* __restrict__ rowptr, const int* __restrict__ adj,
                const float* __restrict__ dinv, const ushort* __restrict__ t,
                const float* __restrict__ bias, float* __restrict__ out, int n) {
    const int i = blockIdx.x * 4 + (threadIdx.x >> 6);
    if (i >= n) return;
    const int lane = threadIdx.x & 63;
    const uint2* t2 = (const uint2*)t;   // [row][64] x uint2 (256 bf16)
    uint2 u = t2[(size_t)i * 64 + lane];
    float a0 = bf2f_lo(u.x), a1 = bf2f_hi(u.x);
    float a2 = bf2f_lo(u.y), a3 = bf2f_hi(u.y);
    int j = rowptr[i];
    const int end = rowptr[i + 1];
    for (; j + 8 <= end; j += 8) {
        int s0 = adj[j],     s1 = adj[j + 1], s2 = adj[j + 2], s3 = adj[j + 3];
        int s4 = adj[j + 4], s5 = adj[j + 5], s6 = adj[j + 6], s7 = adj[j + 7];
        uint2 u0 = t2[(size_t)s0 * 64 + lane];
        uint2 u1 = t2[(size_t)s1 * 64 + lane];
        uint2 u2 = t2[(size_t)s2 * 64 + lane];
        uint2 u3 = t2[(size_t)s3 * 64 + lane];
        uint2 u4 = t2[(size_t)s4 * 64 + lane];
        uint2 u5 = t2[(size_t)s5 * 64 + lane];
        uint2 u6 = t2[(size_t)s6 * 64 + lane];
        uint2 u7 = t2[(size_t)s7 * 64 + lane];
        a0 += bf2f_lo(u0.x) + bf2f_lo(u1.x) + bf2f_lo(u2.x) + bf2f_lo(u3.x);
        a1 += bf2f_hi(u0.x) + bf2f_hi(u1.x) + bf2f_hi(u2.x) + bf2f_hi(u3.x);
        a2 += bf2f_lo(u0.y) + bf2f_lo(u1.y) + bf2f_lo(u2.y) + bf2f_lo(u3.y);
        a3 += bf2f_hi(u0.y) + bf2f_hi(u1.y) + bf2f_hi(u2.y) + bf2f_hi(u3.y);
        a0 += bf2f_lo(u4.x) + bf2f_lo(u5.x) + bf2f_lo(u6.x) + bf2f_lo(u7.x);
        a1 += bf2f_hi(u4.x) + bf2f_hi(u5.x) + bf2f_hi(u6.x) + bf2f_hi(u7.x);
        a2 += bf2f_lo(u4.y) + bf2f_lo(u5.y) + bf2f_lo(u6.y) + bf2f_lo(u7.y);
        a3 += bf2f_hi(u4.y) + bf2f_hi(u5.y) + bf2f_hi(u6.y) + bf2f_hi(u7.y);
    }
    for (; j + 4 <= end; j += 4) {
        int s0 = adj[j], s1 = adj[j + 1], s2 = adj[j + 2], s3 = adj[j + 3];
        uint2 u0 = t2[(size_t)s0 * 64 + lane];
        uint2 u1 = t2[(size_t)s1 * 64 + lane];
        uint2 u2 = t2[(size_t)s2 * 64 + lane];
        uint2 u3 = t2[(size_t)s3 * 64 + lane];
        a0 += bf2f_lo(u0.x) + bf2f_lo(u1.x) + bf2f_lo(u2.x) + bf2f_lo(u3.x);
        a1 += bf2f_hi(u0.x) + bf2f_hi(u1.x) + bf2f_hi(u2.x) + bf2f_hi(u3.x);
        a2 += bf2f_lo(u0.y) + bf2f_lo(u1.y) + bf2f_lo(u2.y) + bf2f_lo(u3.y);
        a3 += bf2f_hi(u0.y) + bf2f_hi(u1.y) + bf2f_hi(u2.y) + bf2f_hi(u3.y);
    }
    for (; j < end; ++j) {
        uint2 us = t2[(size_t)adj[j] * 64 + lane];
        a0 += bf2f_lo(us.x); a1 += bf2f_hi(us.x);
        a2 += bf2f_lo(us.y); a3 += bf2f_hi(us.y);
    }
    const float d = dinv[i];
    const int c0 = lane * 4;
    if (lane < 62) {
        float2 b0 = *(const float2*)&bias[c0];
        float2 b1 = *(const float2*)&bias[c0 + 2];
        float2 o0, o1;
        o0.x = fmaxf(d * a0 + b0.x, 0.0f);
        o0.y = fmaxf(d * a1 + b0.y, 0.0f);
        o1.x = fmaxf(d * a2 + b1.x, 0.0f);
        o1.y = fmaxf(d * a3 + b1.y, 0.0f);
        *(float2*)&out[(size_t)i * 250 + c0] = o0;
        *(float2*)&out[(size_t)i * 250 + c0 + 2] = o1;
    } else if (lane == 62) {   // cols 248,249
        float2 b0 = *(const float2*)&bias[248];
        float2 o0;
        o0.x = fmaxf(d * a0 + b0.x, 0.0f);
        o0.y = fmaxf(d * a1 + b0.y, 0.0f);
        *(float2*)&out[(size_t)i * 250 + 248] = o0;
    }
}

__device__ __forceinline__ void gl16(const ushort* g, ushort* l) {
    __builtin_amdgcn_global_load_lds((const __attribute__((address_space(1))) void*)g,
                                     (__attribute__((address_space(3))) void*)l,
                                     16, 0, 0);
}

// ---------------- GEMM1 (K=128, single tile, no K-loop) ------------------
// h1 = relu(A1[128-panel] @ Bt1[128-colblk]^T + b1). LDS: A,B each
// [16 chunks][128 rows][8 us] = 32 KB -> 64 KB total, 2 blocks/CU.
// One stage (16 gl16/wave) -> one vmcnt(0)+barrier -> 64 MFMA/wave.
#define G1_OFFB 16384

__global__ __launch_bounds__(256, 2)
void k_mfma1(const ushort* __restrict__ A, const ushort* __restrict__ B,
             const float* __restrict__ bias, ushort* __restrict__ outp,
             int M, int CX, int PY) {
    __shared__ __align__(16) ushort smem[32768];   // 64 KiB

    // XCD swizzle: a panel's CX col-blocks get ids ≡ same (mod 8)
    int id = blockIdx.x;
    const int gsz = CX * 8;
    const int nfull = (PY >> 3) * gsz;
    int bx, by;
    if (id < nfull) {
        int gg = id / gsz;
        int r  = id - gg * gsz;
        bx = r >> 3;
        by = gg * 8 + (r & 7);
    } else {
        int rem  = id - nfull;
        int pbase = (PY >> 3) << 3;
        int prem  = PY - pbase;
        by = pbase + rem % prem;
        bx = rem / prem;
    }
    const int brow = by * 128;
    const int bcol = bx * 128;

    const int lane = threadIdx.x & 63;
    const int w    = threadIdx.x >> 6;
    const int g    = lane >> 4;
    const int lr   = lane & 15;
    const int wm   = w >> 1, wn = w & 1;

    // stage full 128x128 tiles: idx = w*8+t in 0..31; chunk c = idx>>1,
    // row-half h = idx&1. lds[c][row][j] = src[row][c*8+j], K=128.
    #pragma unroll
    for (int t = 0; t < 8; ++t) {
        const int idx = w * 8 + t;
        const int c  = idx >> 1;
        const int r0 = (idx & 1) * 64;
        const int doff = c * 1024 + r0 * 8;
        gl16(A + (size_t)(brow + r0 + lane) * 128 + c * 8, smem + doff);
        gl16(B + (size_t)(bcol + r0 + lane) * 128 + c * 8, smem + G1_OFFB + doff);
    }
    asm volatile("s_waitcnt vmcnt(0)" ::: "memory");
    __builtin_amdgcn_sched_barrier(0);
    __builtin_amdgcn_s_barrier();

    f32x4 acc[4][4] = {};
    #pragma unroll
    for (int ks = 0; ks < 4; ++ks) {
        bf16x8 af[4], bh[4];
        const int cb = (ks * 4 + g) * 1024;
        #pragma unroll
        for (int i = 0; i < 4; ++i) {
            af[i] = *(const bf16x8*)(smem + cb + (wm * 64 + i * 16 + lr) * 8);
            bh[i] = *(const bf16x8*)(smem + G1_OFFB + cb + (wn * 64 + i * 16 + lr) * 8);
        }
        #pragma unroll
        for (int mt = 0; mt < 4; ++mt)
            #pragma unroll
            for (int nt = 0; nt < 4; ++nt)
                acc[mt][nt] = __builtin_amdgcn_mfma_f32_16x16x32_bf16(bh[nt], af[mt], acc[mt][nt], 0, 0, 0);
    }

    // epilogue: row = brow+wm*64+mt*16+lr, cols = bcol+wn*64+nt*16+g*4
    #pragma unroll
    for (int mt = 0; mt < 4; ++mt) {
        const int gr = brow + wm * 64 + mt * 16 + lr;
        if (gr >= M) continue;
        #pragma unroll
        for (int nt = 0; nt < 4; ++nt) {
            const int gc0 = bcol + wn * 64 + nt * 16 + g * 4;
            const float4 bv = *(const float4*)&bias[gc0];
            float v0 = fmaxf(acc[mt][nt][0] + bv.x, 0.0f);
            float v1 = fmaxf(acc[mt][nt][1] + bv.y, 0.0f);
            float v2 = fmaxf(acc[mt][nt][2] + bv.z, 0.0f);
            float v3 = fmaxf(acc[mt][nt][3] + bv.w, 0.0f);
            uint2 pk;
            pk.x = (unsigned)f2bf(v0) | ((unsigned)f2bf(v1) << 16);
            pk.y = (unsigned)f2bf(v2) | ((unsigned)f2bf(v3) << 16);
            *(uint2*)(outp + (size_t)gr * 512 + gc0) = pk;
        }
    }
}

// ---------------- GEMM2: t = dinv ⊙ (h1 @ Bt2^T), R12-verified ----------
// Tile 128 rows x 256 cols, BK=32, 4 waves; counted vmcnt(6) dbuf, 48 KiB.
#define OFF_B 4096         // A: 4 chunks * 1024 ushorts
#define SMEM_HALF 12288    // OFF_B + 4*2048  (= 24576 B; x2 = 48 KiB)

__global__ __launch_bounds__(256, 2)
void k_mfma(const ushort* __restrict__ A, const ushort* __restrict__ B,
            const float* __restrict__ rscale, ushort* __restrict__ outp,
            int M, int K, int ldc, int CX, int PY) {
    __shared__ __align__(16) ushort smem[2 * SMEM_HALF];

    int id = blockIdx.x;
    const int gsz = CX * 8;
    const int nfull = (PY >> 3) * gsz;
    int bx, by;
    if (id < nfull) {
        int gg = id / gsz;
        int r  = id - gg * gsz;
        bx = r >> 3;
        by = gg * 8 + (r & 7);
    } else {
        int rem  = id - nfull;
        int pbase = (PY >> 3) << 3;
        int prem  = PY - pbase;
        by = pbase + rem % prem;
        bx = rem / prem;
    }
    const int brow = by * 128;
    const int bcol = bx * 256;

    const int lane = threadIdx.x & 63;
    const int w    = threadIdx.x >> 6;
    const int g    = lane >> 4;
    const int lr   = lane & 15;

    auto STAGE = [&](ushort* buf, int k0) {
        const int kofs = k0 + w * 8;
        #pragma unroll
        for (int t2 = 0; t2 < 2; ++t2)
            gl16(A + (size_t)(brow + t2 * 64 + lane) * K + kofs,
                 buf + w * 1024 + t2 * 512);
        #pragma unroll
        for (int t4 = 0; t4 < 4; ++t4)
            gl16(B + (size_t)(bcol + t4 * 64 + lane) * K + kofs,
                 buf + OFF_B + w * 2048 + t4 * 512);
    };

    f32x4 acc[8][4] = {};

    auto COMPUTE = [&](const ushort* rb) {
        bf16x8 af[8], bh[4];
        #pragma unroll
        for (int nt = 0; nt < 4; ++nt)
            bh[nt] = *(const bf16x8*)(rb + OFF_B + g * 2048 + (w * 64 + nt * 16 + lr) * 8);
        #pragma unroll
        for (int mt = 0; mt < 8; ++mt)
            af[mt] = *(const bf16x8*)(rb + g * 1024 + (mt * 16 + lr) * 8);
        #pragma unroll
        for (int mt = 0; mt < 8; ++mt)
            #pragma unroll
            for (int nt = 0; nt < 4; ++nt)
                acc[mt][nt] = __builtin_amdgcn_mfma_f32_16x16x32_bf16(bh[nt], af[mt], acc[mt][nt], 0, 0, 0);
    };

    STAGE(smem, 0);
    int cur = 0;
    for (int k0 = 32; k0 < K; k0 += 32) {
        STAGE(smem + (cur ^ 1) * SMEM_HALF, k0);
        asm volatile("s_waitcnt vmcnt(6)" ::: "memory");
        __builtin_amdgcn_sched_barrier(0);
        __builtin_amdgcn_s_barrier();
        COMPUTE(smem + cur * SMEM_HALF);
        __builtin_amdgcn_sched_barrier(0);
        __builtin_amdgcn_s_barrier();
        cur ^= 1;
    }
    asm volatile("s_waitcnt vmcnt(0)" ::: "memory");
    __builtin_amdgcn_sched_barrier(0);
    __builtin_amdgcn_s_barrier();
    COMPUTE(smem + cur * SMEM_HALF);

    #pragma unroll
    for (int mt = 0; mt < 8; ++mt) {
        const int gr = brow + mt * 16 + lr;
        if (gr >= M) continue;
        const float rs = rscale[gr];
        #pragma unroll
        for (int nt = 0; nt < 4; ++nt) {
            const int gc0 = bcol + w * 64 + nt * 16 + g * 4;
            uint2 pk;
            pk.x = (unsigned)f2bf(acc[mt][nt][0] * rs) |
                   ((unsigned)f2bf(acc[mt][nt][1] * rs) << 16);
            pk.y = (unsigned)f2bf(acc[mt][nt][2] * rs) |
                   ((unsigned)f2bf(acc[mt][nt][3] * rs) << 16);
            *(uint2*)(outp + (size_t)gr * ldc + gc0) = pk;
        }
    }
}

extern "C" void kernel_launch(void* const* d_in, const int* in_sizes, int n_in,
                              void* d_out, int out_size, void* d_ws, size_t ws_size,
                              hipStream_t stream) {
    const float* x  = (const float*)d_in[0];
    const void*  ei = d_in[1];
    const float* W1 = (const float*)d_in[2];
    const float* b1 = (const float*)d_in[3];
    const float* W2 = (const float*)d_in[4];
    const float* b2 = (const float*)d_in[5];
    float* out = (float*)d_out;

    const int N = N_NODES;
    const int E = in_sizes[1] / 2;
    const int MPAD = 50048;             // 391 * 128
    const int NSCB = (N + 511) / 512;   // 98 scan blocks

    // ---- workspace layout ----
    char* base = (char*)d_ws;
    int*   flag   = (int*)base;                        // 256 B slot
    int*   deg    = (int*)(base + 256);                // [51200]
    int*   rowptr = deg + 51200;
    int*   cur    = rowptr + 51200;
    float* dinv   = (float*)(cur + 51200);
    int*   bsum   = (int*)(dinv + 51200);              // [128]
    int*   adj    = bsum + 128;                        // [E]
    char*  p      = (char*)(adj + ((E + 63) & ~63));
    ushort* A1hi  = (ushort*)p;  p += (size_t)MPAD * 128 * 2;
    ushort* A1xx  = (ushort*)p;  p += (size_t)MPAD * 128 * 2;  // pad (tbuf tail)
    ushort* tbuf  = A1hi;        // [N][256] bf16, aliases A1hi+pad (dead after GEMM1)
    ushort* h1hi  = (ushort*)p;  p += (size_t)MPAD * 512 * 2;  // plain bf16
    ushort* Bt1   = (ushort*)p;  p += 512 * 128 * 2;
    ushort* Bt2   = (ushort*)p;  p += 256 * 512 * 2;
    ushort* xs    = (ushort*)p;  p += (size_t)MPAD * 128 * 2;  // bf16 dinv*x
    (void)A1xx;

    // 1. init (detect + deg-zero + weight prep)
    const int initBlocks = (512 * 128 + 256 * 512 + 255) / 256;   // 768 >= N/256
    k_init<<<initBlocks, 256, 0, stream>>>(ei, flag, deg, N, W1, W2, Bt1, Bt2);
    k_hist<<<(E / 4 + 255) / 256, 256, 0, stream>>>(ei, flag, deg, E);
    k_scanA<<<NSCB, 512, 0, stream>>>(deg, rowptr + 1, bsum, N);
    k_scanC<<<NSCB, 512, 0, stream>>>(deg, rowptr, bsum, cur, dinv, N, NSCB);
    k_fill<<<((E + 255) / 256) * 8, 256, 0, stream>>>(ei, flag, cur, adj, E);

    // 2. pre-scaled features
    k_scale<<<(N * 64 + 255) / 256, 256, 0, stream>>>(x, dinv, xs, N);

    // 3. layer-1 aggregation -> A1 (bf16)  [N,128]
    k_pull128b<<<(N + 3) / 4, 256, 0, stream>>>(rowptr, adj, dinv, xs, A1hi, N);

    // 4. h1 = relu(A1 @ W1 + b1) -> bf16 [N,512]  (single-K-tile GEMM)
    k_mfma1<<<4 * 391, 256, 0, stream>>>(A1hi, Bt1, b1, h1hi, N, 4, 391);

    // 5. t = bf16( dinv[row] * (h1 @ W2) )  [N,256]
    k_mfma<<<1 * 391, 256, 0, stream>>>(h1hi, Bt2, dinv, tbuf, N, 512, 256, 1, 391);

    // 6. layer-2 aggregation + bias + relu -> out  [N,250]
    k_pull250v<<<(N + 3) / 4, 256, 0, stream>>>(rowptr, adj, dinv, tbuf, b2, out, N);
}